// Round 3
// baseline (347.275 us; speedup 1.0000x reference)
//
#include <hip/hip_runtime.h>

#define TT 1024
#define NN 256
#define CC 128
#define SS 128
#define NEG (-1e30f)
#define LOG2E 1.4426950408889634f
#define LN2 0.6931471805599453f

// log-sum-exp in log2 domain, 2-arg: log2(2^a + 2^b)  -- arithmetic kept
// bit-identical to round 2 (absmax was 0.0); this round only fixes storage.
__device__ __forceinline__ float lae2(float a, float b) {
    float m = fmaxf(a, b);
    float mn = fminf(a, b);
    float s = 1.0f + __builtin_amdgcn_exp2f(mn - m);
    return m + __builtin_amdgcn_logf(s);   // v_log_f32 is log2
}
// 3-arg: log2(2^a + 2^b + 2^c)
__device__ __forceinline__ float lae3(float a, float b, float c) {
    float m = fmaxf(fmaxf(a, b), c);       // fuses to v_max3_f32
    float s = __builtin_amdgcn_exp2f(a - m) + __builtin_amdgcn_exp2f(b - m)
            + __builtin_amdgcn_exp2f(c - m);
    return m + __builtin_amdgcn_logf(s);
}

// One wave (64 lanes) per batch sample. Lane i owns extended positions
// l = 4i .. 4i+3 (a0..a3); lane 63 additionally owns l=256 (a4).
// Cross-lane dep per step: only alpha[4i-1] = prev lane's a3 (one shfl_up).
//
// ROUND-1/2 LESSON: C arrays in the hot loop went to scratch even with
// static-after-unroll indices (VGPR=24/28, WRITE_SIZE=9MB). The 16-deep
// prefetch pipeline is therefore NAMED SCALARS via macros — nothing the
// compiler can demote to local memory.
__global__ __launch_bounds__(64, 1) void ctc_alpha_kernel(
    const float* __restrict__ lp, const int* __restrict__ tgt,
    const int* __restrict__ ilen_p, const int* __restrict__ tlen_p,
    float* __restrict__ ws)
{
    const int n = blockIdx.x;
    const int lane = threadIdx.x;
    const int ilen = ilen_p[n];
    const int tlen = tlen_p[n];

    // time-invariant gather indices: ext[4i+1]=tgt[2i], ext[4i+3]=tgt[2i+1]
    const int te = tgt[n * SS + 2 * lane]     & (CC - 1);
    const int to = tgt[n * SS + 2 * lane + 1] & (CC - 1);
    const int tprev = __shfl_up(to, 1, 64);   // tgt[2i-1]
    const bool skip1 = (lane > 0) && (te != tprev); // l=4i+1: ext[l]!=ext[l-2]
    const bool skip3 = (to != te);                  // l=4i+3

    const float* base = lp + (size_t)n * CC;        // + t*NN*CC per step
    const long long stride = (long long)NN * CC;

#define DECLS(d) float rb##d, r1##d, r2##d;
    DECLS(0)  DECLS(1)  DECLS(2)  DECLS(3)
    DECLS(4)  DECLS(5)  DECLS(6)  DECLS(7)
    DECLS(8)  DECLS(9)  DECLS(10) DECLS(11)
    DECLS(12) DECLS(13) DECLS(14) DECLS(15)

#define LOAD0(d) { const float* p = base + (long long)(d) * stride; \
                   rb##d = p[0]; r1##d = p[te]; r2##d = p[to]; }
    LOAD0(0)  LOAD0(1)  LOAD0(2)  LOAD0(3)
    LOAD0(4)  LOAD0(5)  LOAD0(6)  LOAD0(7)
    LOAD0(8)  LOAD0(9)  LOAD0(10) LOAD0(11)
    LOAD0(12) LOAD0(13) LOAD0(14) LOAD0(15)

    // pre-state: running one normal step from this produces the exact alpha0
    float a0 = (lane == 0) ? 0.0f : NEG;
    float a1 = NEG, a2 = NEG, a3 = NEG, a4 = NEG;

    // consume slot d (current step), then branchless-prefetch t0+d+16 into it
#define BODY(d) { \
    const float eb = rb##d * LOG2E; \
    const float e1 = r1##d * LOG2E; \
    const float e3 = r2##d * LOG2E; \
    { int tn = t0 + (d) + 16; tn = (tn < TT) ? tn : (TT - 1); \
      const float* p = base + (long long)tn * stride; \
      rb##d = p[0]; r1##d = p[te]; r2##d = p[to]; } \
    const float s3 = __shfl_up(a3, 1, 64); \
    const float p3 = (lane == 0) ? NEG : s3; \
    const float n0 = eb + lae2(a0, p3); \
    const float n1 = e1 + lae3(a1, a0, skip1 ? p3 : NEG); \
    const float n2 = eb + lae2(a2, a1); \
    const float n3 = e3 + lae3(a3, a2, skip3 ? a1 : NEG); \
    const float n4 = eb + lae2(a4, a3); \
    a0 = n0; a1 = n1; a2 = n2; a3 = n3; a4 = n4; }

    int t0 = 0;
    for (; t0 + 16 <= ilen; t0 += 16) {
        BODY(0)  BODY(1)  BODY(2)  BODY(3)
        BODY(4)  BODY(5)  BODY(6)  BODY(7)
        BODY(8)  BODY(9)  BODY(10) BODY(11)
        BODY(12) BODY(13) BODY(14) BODY(15)
    }

    // tail: slot d holds t = t0 + d (prefetched by the last main iteration).
    // Conditions are wave-uniform (t0, ilen uniform) so shfl is safe.
#define TAILB(d) if (t0 + (d) < ilen) { \
    const float eb = rb##d * LOG2E; \
    const float e1 = r1##d * LOG2E; \
    const float e3 = r2##d * LOG2E; \
    const float s3 = __shfl_up(a3, 1, 64); \
    const float p3 = (lane == 0) ? NEG : s3; \
    const float n0 = eb + lae2(a0, p3); \
    const float n1 = e1 + lae3(a1, a0, skip1 ? p3 : NEG); \
    const float n2 = eb + lae2(a2, a1); \
    const float n3 = e3 + lae3(a3, a2, skip3 ? a1 : NEG); \
    const float n4 = eb + lae2(a4, a3); \
    a0 = n0; a1 = n1; a2 = n2; a3 = n3; a4 = n4; }

    TAILB(0)  TAILB(1)  TAILB(2)  TAILB(3)
    TAILB(4)  TAILB(5)  TAILB(6)  TAILB(7)
    TAILB(8)  TAILB(9)  TAILB(10) TAILB(11)
    TAILB(12) TAILB(13) TAILB(14) TAILB(15)

    // final: loss = -logaddexp(alpha[2*tl], alpha[2*tl-1]) / tl
    __shared__ float alds[260];
    alds[4 * lane + 0] = a0;
    alds[4 * lane + 1] = a1;
    alds[4 * lane + 2] = a2;
    alds[4 * lane + 3] = a3;
    if (lane == 63) alds[256] = a4;
    __syncthreads();
    if (lane == 0) {
        const int idx = 2 * tlen;
        const float r = lae2(alds[idx], alds[idx - 1]);  // log2 domain
        ws[n] = -(r * LN2) / (float)tlen;                // back to ln, /tl
    }
}

__global__ __launch_bounds__(64) void ctc_reduce_kernel(
    const float* __restrict__ ws, float* __restrict__ out)
{
    const int lane = threadIdx.x;
    float s = ws[lane] + ws[lane + 64] + ws[lane + 128] + ws[lane + 192];
    #pragma unroll
    for (int off = 32; off > 0; off >>= 1)
        s += __shfl_down(s, off, 64);
    if (lane == 0) out[0] = s * (1.0f / NN);
}

extern "C" void kernel_launch(void* const* d_in, const int* in_sizes, int n_in,
                              void* d_out, int out_size, void* d_ws, size_t ws_size,
                              hipStream_t stream) {
    const float* lp  = (const float*)d_in[0];   // (T, N, C) f32
    const int*   tgt = (const int*)d_in[1];     // (N, S) i32
    const int*   il  = (const int*)d_in[2];     // (N,) i32
    const int*   tl  = (const int*)d_in[3];     // (N,) i32
    float* out = (float*)d_out;
    float* ws  = (float*)d_ws;

    hipLaunchKernelGGL(ctc_alpha_kernel, dim3(NN), dim3(64), 0, stream,
                       lp, tgt, il, tl, ws);
    hipLaunchKernelGGL(ctc_reduce_kernel, dim3(1), dim3(64), 0, stream, ws, out);
}